// Round 5
// baseline (2544.983 us; speedup 1.0000x reference)
//
#include <hip/hip_runtime.h>
#include <math.h>

typedef __attribute__((ext_vector_type(8))) _Float16 f16x8;       // 8 f16 = 4 VGPR (MFMA A/B frag)
typedef __attribute__((ext_vector_type(8))) short bf16x8;         // 8 bf16 = 4 VGPR
typedef __attribute__((ext_vector_type(4))) float f32x4;          // MFMA C/D frag
typedef __attribute__((ext_vector_type(8))) unsigned short ushort8;

// ---------------- dtype helpers ----------------

__device__ __forceinline__ float bf2f(unsigned short u) {
    union { unsigned int i; float f; } x; x.i = ((unsigned int)u) << 16; return x.f;
}
__device__ __forceinline__ unsigned short f2bf(float f) {
    union { float f; unsigned int i; } x; x.f = f;
    unsigned int i = x.i;
    unsigned int r = (i + 0x7FFFu + ((i >> 16) & 1u)) >> 16;   // RNE
    return (unsigned short)r;
}
__device__ __forceinline__ float h2f(unsigned short u) {
    _Float16 h; __builtin_memcpy(&h, &u, 2); return (float)h;
}
__device__ __forceinline__ unsigned short f2h(float f) {
    _Float16 h = (_Float16)f; unsigned short u; __builtin_memcpy(&u, &h, 2); return u;
}
__device__ __forceinline__ float ld1(const void* p, long i, bool bf) {
    return bf ? bf2f(((const unsigned short*)p)[i]) : ((const float*)p)[i];
}
__device__ __forceinline__ float4 ld4(const void* p, long i, bool bf) {
    if (bf) {
        ushort4 u = *(const ushort4*)((const unsigned short*)p + i);
        return make_float4(bf2f(u.x), bf2f(u.y), bf2f(u.z), bf2f(u.w));
    }
    return *(const float4*)((const float*)p + i);
}

// Detect whether float tensors are bf16-packed (see round 0 notes).
__global__ void k_detect(const unsigned int* __restrict__ x, int* __restrict__ flag) {
    int t = threadIdx.x;
    int hits = 0;
    for (int i = 0; i < 64; i++) {
        unsigned int w = x[t * 64 + i];
        unsigned int e = (w >> 7) & 0xFF;
        hits += (e >= 0x70 && e <= 0x85) ? 1 : 0;
    }
    __shared__ int sh[256];
    sh[t] = hits;
    __syncthreads();
    for (int off = 128; off; off >>= 1) {
        if (t < off) sh[t] += sh[t + off];
        __syncthreads();
    }
    if (t == 0) *flag = (sh[0] > 8192) ? 1 : 0;   // 16384 words total
}

// ---------------- weight prep: W[K][N] -> WT[Npad][K] f16 hi/lo + bf16 ----------------
// grid (K/256, Npad); rows n >= N zero-filled (lets GEMM read a full 128-tile).

__global__ void k_prep(const void* __restrict__ W, int K, int N,
                       _Float16* __restrict__ outH, _Float16* __restrict__ outL,
                       unsigned short* __restrict__ outBf, const int* __restrict__ dflag) {
    const int k = blockIdx.x * 256 + threadIdx.x;
    const int n = blockIdx.y;
    const bool bf = (*dflag != 0);
    float w = (n < N) ? ld1(W, (long)k * N + n, bf) : 0.f;
    long idx = (long)n * K + k;
    _Float16 h = (_Float16)w;
    outH[idx] = h;
    outL[idx] = (_Float16)(w - (float)h);
    outBf[idx] = f2bf(w);
}

// ---------------- CSR build (counting sort by dst) ----------------

__global__ void k_hist(const int* __restrict__ dst, int E, int* __restrict__ counts) {
    int i = blockIdx.x * blockDim.x + threadIdx.x;
    if (i < E) atomicAdd(&counts[dst[i]], 1);
}

__global__ void k_scan_a(const int* __restrict__ counts, int N,
                         int* __restrict__ ex, int* __restrict__ bsums) {
    __shared__ int s[256];
    int t = threadIdx.x;
    int base = blockIdx.x * 1024;
    int v[4]; int sum = 0;
    #pragma unroll
    for (int j = 0; j < 4; j++) {
        int idx = base + t * 4 + j;
        v[j] = (idx < N) ? counts[idx] : 0;
        sum += v[j];
    }
    s[t] = sum;
    __syncthreads();
    for (int off = 1; off < 256; off <<= 1) {
        int x = (t >= off) ? s[t - off] : 0;
        __syncthreads();
        s[t] += x;
        __syncthreads();
    }
    int run = (t > 0) ? s[t - 1] : 0;
    #pragma unroll
    for (int j = 0; j < 4; j++) {
        int idx = base + t * 4 + j;
        if (idx < N) ex[idx] = run;
        run += v[j];
    }
    if (t == 255) bsums[blockIdx.x] = s[255];
}

__global__ void k_scan_b(int* __restrict__ bsums, int nb) {
    __shared__ int s[256];
    int t = threadIdx.x;
    s[t] = (t < nb) ? bsums[t] : 0;
    __syncthreads();
    for (int off = 1; off < 256; off <<= 1) {
        int x = (t >= off) ? s[t - off] : 0;
        __syncthreads();
        s[t] += x;
        __syncthreads();
    }
    if (t < nb) bsums[t] = (t > 0) ? s[t - 1] : 0;
}

__global__ void k_scan_c(const int* __restrict__ ex, const int* __restrict__ bsums,
                         int N, int E, int* __restrict__ row_ptr) {
    int i = blockIdx.x * blockDim.x + threadIdx.x;
    if (i < N) row_ptr[i] = ex[i] + bsums[i >> 10];
    if (i == 0) row_ptr[N] = E;
}

__global__ void k_scatter(const int* __restrict__ src, const int* __restrict__ dst,
                          const void* __restrict__ ewin, const int* __restrict__ dflag,
                          const int* __restrict__ row_ptr, int* __restrict__ cursor,
                          int E, int* __restrict__ es, float* __restrict__ ew) {
    int i = blockIdx.x * blockDim.x + threadIdx.x;
    if (i >= E) return;
    bool bf = (*dflag != 0);
    int d = dst[i];
    int p = row_ptr[d] + atomicAdd(&cursor[d], 1);
    es[p] = src[i];
    ew[p] = ld1(ewin, i, bf);
}

// ---------------- MFMA GEMM: C = act(A[M,K] @ W[K,N] (+ bias)) ----------------
// 128x128 tile, 256 threads (4 waves, 2x2), BK=32. Weights PRE-TRANSPOSED
// ([Npad][K] f16 hi/lo + bf16 planes). BOTH A and B tiles staged through LDS
// with the SAME conflict-free raw-copy pattern (thread t -> row t>>1, k-half
// (t&1)*16, 2x 16B): no transpose VALU, no bank-conflicted ds_writes, and
// global->LDS->MFMA keeps load latency off the per-K-step critical path
// (round-4 lesson: B-direct-from-global was latency-bound).
// Multi-pass design: the rare fp32 paths run extra sequential K-loop passes
// (re-staging) instead of resident lo-planes -> LDS stays 20 KB:
//   a_mode==1 (raw bf16 A): 1 pass  (A x Bbf, bf16 MFMA)
//   a_mode==2 (f16 A), bf16 wts: 1 pass (A x Bh)
//   a_mode==2, fp32 wts: 2 passes (A x Bh, A x Bl)
//   a_mode==0 (fp32 A): 3 passes (Ah x Bh, Al x Bh, Ah x Bl)
// Operand-swapped MFMA: acc[i][j] = mfma(b[j], a[i], acc) -> D^T layout:
//   m = m0+wm+i*16+(lane&15), n = n0+wn+j*16+(lane>>4)*4+reg
// -> each lane stores 4 consecutive n (8B f16 / 16B fp32), coalesced.

__global__ __launch_bounds__(256) void k_gemm(
    const void* __restrict__ A,
    const _Float16* __restrict__ BTh, const _Float16* __restrict__ BTl,
    const unsigned short* __restrict__ BTbf,
    const void* __restrict__ bias, void* __restrict__ C, int M, int K, int N,
    int a_kind, int c_mode, int act, const int* __restrict__ dflag)
{
    const bool inbf = (*dflag != 0);
    const int  a_mode = (a_kind == 2) ? 2 : (inbf ? 1 : 0);   // 0 fp32, 1 bf16 raw, 2 f16
    const bool a_lo = (a_mode == 0);
    const bool b_lo = !inbf;

    // [row][k], k contiguous; pad 32->40 elems: 16-row-strided b128 reads ~2-way (free)
    __shared__ unsigned short Ah[128][40];
    __shared__ unsigned short Bh[128][40];

    const int t  = threadIdx.x;
    const int m0 = blockIdx.y * 128;        // grid: x = n-tiles (fast) -> A-panel L2 reuse
    const int n0 = blockIdx.x * 128;

    const int lane = t & 63;
    const int wv   = t >> 6;
    const int wm   = (wv & 1) * 64;         // wave's 64x64 quadrant
    const int wn   = (wv >> 1) * 64;
    const int lr   = lane & 15;             // frag index (m for A, n for B)
    const int lk   = (lane >> 4) * 8;       // frag k-offset (8 elems = b128)

    f32x4 acc[4][4];
    const f32x4 vzero = {0.f, 0.f, 0.f, 0.f};
    #pragma unroll
    for (int i = 0; i < 4; i++)
        #pragma unroll
        for (int j = 0; j < 4; j++) acc[i][j] = vzero;

    // staging map: thread -> (row = t>>1, k-half = (t&1)*16), 2x 16B per plane
    const int  ar  = t >> 1;
    const int  ak  = (t & 1) * 16;
    const long agm = (long)(m0 + ar);
    const long brow = (long)(n0 + ar) * K;  // B staging source row (pre-transposed)

    // pass table
    int npass;
    const unsigned short* bpl[3];
    int asel[3];                            // 0 = hi plane of A, 1 = lo plane
    if (a_mode == 1) {
        npass = 1; bpl[0] = BTbf; asel[0] = 0;
    } else {
        npass = 0;
        bpl[npass] = (const unsigned short*)BTh; asel[npass++] = 0;
        if (a_lo) { bpl[npass] = (const unsigned short*)BTh; asel[npass++] = 1; }
        if (b_lo) { bpl[npass] = (const unsigned short*)BTl; asel[npass++] = 0; }
    }

    for (int p = 0; p < npass; ++p) {
        const unsigned short* BT = bpl[p];
        const int sel = asel[p];
        for (int k0 = 0; k0 < K; k0 += 32) {
            // ---- stage A tile (128 x 32) + B tile (128 x 32), same pattern ----
            #pragma unroll
            for (int c = 0; c < 2; c++) {
                long abase = agm * K + k0 + ak + c * 8;
                if (a_mode != 0) {          // raw 16B copy (f16 or bf16 bits)
                    uint4 raw = make_uint4(0, 0, 0, 0);
                    if (agm < M) raw = *(const uint4*)((const unsigned short*)A + abase);
                    *(uint4*)&Ah[ar][ak + c * 8] = raw;
                } else {                    // fp32 -> exact f16 hi or lo
                    float4 v0 = make_float4(0.f, 0.f, 0.f, 0.f), v1 = v0;
                    if (agm < M) {
                        v0 = *(const float4*)((const float*)A + abase);
                        v1 = *(const float4*)((const float*)A + abase + 4);
                    }
                    float f[8] = {v0.x, v0.y, v0.z, v0.w, v1.x, v1.y, v1.z, v1.w};
                    union { _Float16 h[8]; uint4 q; } Q;
                    #pragma unroll
                    for (int e = 0; e < 8; e++) {
                        _Float16 hh = (_Float16)f[e];
                        Q.h[e] = sel ? (_Float16)(f[e] - (float)hh) : hh;
                    }
                    *(uint4*)&Ah[ar][ak + c * 8] = Q.q;
                }
                *(uint4*)&Bh[ar][ak + c * 8] =
                    *(const uint4*)&BT[brow + k0 + ak + c * 8];
            }
            __syncthreads();

            if (a_mode == 1) {
                bf16x8 a[4], b[4];
                #pragma unroll
                for (int f = 0; f < 4; f++) {
                    a[f] = *(const bf16x8*)&Ah[wm + f * 16 + lr][lk];
                    b[f] = *(const bf16x8*)&Bh[wn + f * 16 + lr][lk];
                }
                #pragma unroll
                for (int i = 0; i < 4; i++)
                    #pragma unroll
                    for (int j = 0; j < 4; j++)
                        acc[i][j] = __builtin_amdgcn_mfma_f32_16x16x32_bf16(b[j], a[i], acc[i][j], 0, 0, 0);
            } else {
                f16x8 a[4], b[4];
                #pragma unroll
                for (int f = 0; f < 4; f++) {
                    a[f] = *(const f16x8*)&Ah[wm + f * 16 + lr][lk];
                    b[f] = *(const f16x8*)&Bh[wn + f * 16 + lr][lk];
                }
                #pragma unroll
                for (int i = 0; i < 4; i++)
                    #pragma unroll
                    for (int j = 0; j < 4; j++)
                        acc[i][j] = __builtin_amdgcn_mfma_f32_16x16x32_f16(b[j], a[i], acc[i][j], 0, 0, 0);
            }
            __syncthreads();
        }
    }

    // ---- epilogue (swapped D layout): lane owns 4 consecutive n per m-row ----
    const bool has_bias = (bias != nullptr);
    const int  nb4 = (lane >> 4) * 4;
    #pragma unroll
    for (int i = 0; i < 4; i++) {
        int m = m0 + wm + i * 16 + lr;
        if (m >= M) continue;
        #pragma unroll
        for (int j = 0; j < 4; j++) {
            int nb = n0 + wn + j * 16 + nb4;
            if (nb >= N) continue;          // N % 4 == 0 always
            float4 bv = has_bias ? ld4(bias, nb, inbf) : make_float4(0.f, 0.f, 0.f, 0.f);
            float v0 = acc[i][j][0] + bv.x;
            float v1 = acc[i][j][1] + bv.y;
            float v2 = acc[i][j][2] + bv.z;
            float v3 = acc[i][j][3] + bv.w;
            if (act) {
                v0 = fmaxf(v0, 0.f); v1 = fmaxf(v1, 0.f);
                v2 = fmaxf(v2, 0.f); v3 = fmaxf(v3, 0.f);
            }
            if (c_mode == 2) {
                ushort4 o; o.x = f2h(v0); o.y = f2h(v1); o.z = f2h(v2); o.w = f2h(v3);
                *(ushort4*)&((unsigned short*)C)[(long)m * N + nb] = o;
            } else {
                *(float4*)&((float*)C)[(long)m * N + nb] = make_float4(v0, v1, v2, v3);
            }
        }
    }
}

// ---------------- SPMM: out[d] = act(sum_e w[e]*sup[src[e]] + bias), F=256 ----------------
// One wave per dst node, split into two 32-lane halves, each half owns a
// different edge per iteration; lane (l&31) owns 8 feats (16B ushort8 load).

__global__ __launch_bounds__(256) void k_spmm(
    const unsigned short* __restrict__ sup, const int* __restrict__ es,
    const float* __restrict__ ew, const int* __restrict__ row_ptr,
    const void* __restrict__ bias, unsigned short* __restrict__ out,
    int Nn, int act, const int* __restrict__ dflag)
{
    const int wave = threadIdx.x >> 6;
    const int lane = threadIdx.x & 63;
    const int node = blockIdx.x * 4 + wave;
    if (node >= Nn) return;
    const bool bf = (*dflag != 0);

    const int half = lane >> 5;          // 0 or 1
    const int fl   = (lane & 31) * 8;    // feature base (8 f16 = 16 B)

    const int e0 = row_ptr[node], e1 = row_ptr[node + 1];
    float acc[8] = {};

    #pragma unroll 4
    for (int e = e0 + half; e < e1; e += 2) {
        int s = es[e];
        float w = ew[e];
        ushort8 u = *(const ushort8*)&sup[(long)s * 256 + fl];
        #pragma unroll
        for (int i = 0; i < 8; i++) acc[i] += w * h2f(u[i]);
    }

    #pragma unroll
    for (int i = 0; i < 8; i++) acc[i] += __shfl_xor(acc[i], 32, 64);

    if (half == 0) {
        float4 b0 = ld4(bias, fl, bf);
        float4 b1 = ld4(bias, fl + 4, bf);
        float bb[8] = {b0.x, b0.y, b0.z, b0.w, b1.x, b1.y, b1.z, b1.w};
        ushort8 o;
        #pragma unroll
        for (int i = 0; i < 8; i++) {
            float v = acc[i] + bb[i];
            if (act) v = fmaxf(v, 0.f);
            o[i] = f2h(v);
        }
        *(ushort8*)&out[(long)node * 256 + fl] = o;
    }
}

// ---------------- softmax over NC classes, one wave per row ----------------

__global__ __launch_bounds__(256) void k_softmax(
    const float* __restrict__ logits, void* __restrict__ out, int M, int NC,
    const int* __restrict__ dflag)
{
    const int wave = threadIdx.x >> 6;
    const int lane = threadIdx.x & 63;
    const int row = blockIdx.x * 4 + wave;
    if (row >= M) return;
    const bool bf = (*dflag != 0);

    float v = (lane < NC) ? logits[(long)row * NC + lane] : -INFINITY;
    float m = v;
    #pragma unroll
    for (int off = 32; off; off >>= 1) m = fmaxf(m, __shfl_xor(m, off, 64));
    float p = (lane < NC) ? expf(v - m) : 0.f;
    float s = p;
    #pragma unroll
    for (int off = 32; off; off >>= 1) s += __shfl_xor(s, off, 64);
    if (lane < NC) {
        float r = p / s;
        if (bf) ((unsigned short*)out)[(long)row * NC + lane] = f2bf(r);
        else    ((float*)out)[(long)row * NC + lane] = r;
    }
}

// ---------------- orchestration ----------------

extern "C" void kernel_launch(void* const* d_in, const int* in_sizes, int n_in,
                              void* d_out, int out_size, void* d_ws, size_t ws_size,
                              hipStream_t stream) {
    const void* x    = d_in[0];
    const int*  esrc = (const int*)d_in[1];
    const int*  edst = (const int*)d_in[2];
    const void* ewin = d_in[3];
    const void* w1 = d_in[4],  *b1 = d_in[5];
    const void* w2 = d_in[6],  *b2 = d_in[7];
    const void* wc1 = d_in[8], *bc1 = d_in[9];
    const void* wc2 = d_in[10], *bc2 = d_in[11];
    const void* wc3 = d_in[12], *bc3 = d_in[13];
    const void* wc4 = d_in[14], *bc4 = d_in[15];

    const int HID  = in_sizes[5];                 // 256
    const int IND  = in_sizes[4] / HID;           // 512
    const int HID2 = in_sizes[9];                 // 512
    const int NC   = in_sizes[15];                // 40
    const int M    = in_sizes[0] / IND;           // 100000
    const int E    = in_sizes[1];                 // 3200000

    char* ws = (char*)d_ws;
    int* dflag = (int*)ws;                                        // 256 B slot
    unsigned short* bufA = (unsigned short*)(ws + 256);           // sup (f16, 51.2 MB used)
    unsigned short* bufB = (unsigned short*)(ws + 256 + 102400000L);  // h1/h2 (f16)
    char*  wsC  = ws + 256 + 204800000L;                          // h3/h5 (f16) / CSR
    char*  wsD  = wsC + 204800000L;                               // h4 (f16) + WT tail
    unsigned short* bufC = (unsigned short*)wsC;
    unsigned short* bufD = (unsigned short*)wsD;

    // CSR arrays live inside bufC's region (dead before the MLP starts)
    int* counts  = (int*)wsC;
    int* row_ptr = counts + 100352;
    int* cursor  = row_ptr + 100352;
    int* bsums   = cursor + 100352;
    int* ex      = bsums + 1024;
    int* es      = ex + 100352;
    float* ewS   = (float*)(es + E);

    float* logits = (float*)bufA;   // reuse after support2 is dead (16 MB)

    // pre-transposed weight planes live in the tail of the h4 region
    // (h4 f16 uses only the first 102.4 MB of the 204.8 MB slot)
    _Float16* P = (_Float16*)(wsD + 103000000L);
    // per matrix: [H plane][L plane][Bf plane], each Npad*K elems (2 B each)
    const long s_w1 = 256L * 512, s_w2 = 256L * 256, s_c1 = 512L * 256;
    const long s_c2 = 512L * 512, s_c3 = 512L * 512, s_c4 = 128L * 512;
    _Float16 *w1h = P,              *w1l = w1h + s_w1; unsigned short* w1b = (unsigned short*)(w1l + s_w1);
    _Float16 *w2h = (_Float16*)(w1b + s_w1), *w2l = w2h + s_w2; unsigned short* w2b = (unsigned short*)(w2l + s_w2);
    _Float16 *c1h = (_Float16*)(w2b + s_w2), *c1l = c1h + s_c1; unsigned short* c1b = (unsigned short*)(c1l + s_c1);
    _Float16 *c2h = (_Float16*)(c1b + s_c1), *c2l = c2h + s_c2; unsigned short* c2b = (unsigned short*)(c2l + s_c2);
    _Float16 *c3h = (_Float16*)(c2b + s_c2), *c3l = c3h + s_c3; unsigned short* c3b = (unsigned short*)(c3l + s_c3);
    _Float16 *c4h = (_Float16*)(c3b + s_c3), *c4l = c4h + s_c4; unsigned short* c4b = (unsigned short*)(c4l + s_c4);

    // 0. dtype sniff
    k_detect<<<1, 256, 0, stream>>>((const unsigned int*)x, dflag);

    // 0b. weight prep (transpose + f16 hi/lo + bf16), all tiny
    k_prep<<<dim3(IND / 256, HID),  256, 0, stream>>>(w1,  IND,  HID,  w1h, w1l, w1b, dflag);
    k_prep<<<dim3(HID / 256, HID),  256, 0, stream>>>(w2,  HID,  HID,  w2h, w2l, w2b, dflag);
    k_prep<<<dim3(HID / 256, HID2), 256, 0, stream>>>(wc1, HID,  HID2, c1h, c1l, c1b, dflag);
    k_prep<<<dim3(HID2 / 256, HID2),256, 0, stream>>>(wc2, HID2, HID2, c2h, c2l, c2b, dflag);
    k_prep<<<dim3(HID2 / 256, HID2),256, 0, stream>>>(wc3, HID2, HID2, c3h, c3l, c3b, dflag);
    k_prep<<<dim3(HID2 / 256, 128), 256, 0, stream>>>(wc4, HID2, NC,   c4h, c4l, c4b, dflag);

    // 1. CSR build
    hipMemsetAsync(counts, 0, 100352 * sizeof(int), stream);
    hipMemsetAsync(cursor, 0, 100352 * sizeof(int), stream);
    k_hist<<<(E + 255) / 256, 256, 0, stream>>>(edst, E, counts);
    int nb = (M + 1023) / 1024;                                   // 98
    k_scan_a<<<nb, 256, 0, stream>>>(counts, M, ex, bsums);
    k_scan_b<<<1, 256, 0, stream>>>(bsums, nb);
    k_scan_c<<<(M + 255) / 256, 256, 0, stream>>>(ex, bsums, M, E, row_ptr);
    k_scatter<<<(E + 255) / 256, 256, 0, stream>>>(esrc, edst, ewin, dflag, row_ptr, cursor, E, es, ewS);

    const int gm128 = (M + 127) / 128;   // 782
    dim3 blk(256);

    // 2. support1 = x @ w1                      [M,512]@[512,256] -> bufA (f16)
    k_gemm<<<dim3(HID / 128, gm128), blk, 0, stream>>>(x, w1h, w1l, w1b, nullptr, bufA, M, IND, HID, 0, 2, 0, dflag);
    // 3. h1 = relu(spmm(support1) + b1)        -> bufB (f16)
    k_spmm<<<(M + 3) / 4, blk, 0, stream>>>(bufA, es, ewS, row_ptr, b1, bufB, M, 1, dflag);
    // 4. support2 = h1 @ w2                    -> bufA (f16)
    k_gemm<<<dim3(HID / 128, gm128), blk, 0, stream>>>(bufB, w2h, w2l, w2b, nullptr, bufA, M, HID, HID, 2, 2, 0, dflag);
    // 5. h2 = spmm(support2) + b2              -> bufB (f16)
    k_spmm<<<(M + 3) / 4, blk, 0, stream>>>(bufA, es, ewS, row_ptr, b2, bufB, M, 0, dflag);
    // 6. h3 = relu(h2 @ wc1 + bc1)             [M,256]@[256,512] -> bufC (f16, CSR now dead)
    k_gemm<<<dim3(HID2 / 128, gm128), blk, 0, stream>>>(bufB, c1h, c1l, c1b, bc1, bufC, M, HID, HID2, 2, 2, 1, dflag);
    // 7. h4 = relu(h3 @ wc2 + bc2)             -> bufD (f16)
    k_gemm<<<dim3(HID2 / 128, gm128), blk, 0, stream>>>(bufC, c2h, c2l, c2b, bc2, bufD, M, HID2, HID2, 2, 2, 1, dflag);
    // 8. h5 = relu(h4 @ wc3 + bc3)             -> bufC (f16)
    k_gemm<<<dim3(HID2 / 128, gm128), blk, 0, stream>>>(bufD, c3h, c3l, c3b, bc3, bufC, M, HID2, HID2, 2, 2, 1, dflag);
    // 9. logits = h5 @ wc4 + bc4               [M,512]@[512,40] -> bufA (fp32)
    k_gemm<<<dim3(1, gm128), blk, 0, stream>>>(bufC, c4h, c4l, c4b, bc4, logits, M, HID2, NC, 2, 0, 0, dflag);
    // 10. softmax -> d_out
    k_softmax<<<(M + 3) / 4, blk, 0, stream>>>(logits, d_out, M, NC, dflag);
}

// Round 6
// 2148.879 us; speedup vs baseline: 1.1843x; 1.1843x over previous
//
#include <hip/hip_runtime.h>
#include <math.h>

typedef __attribute__((ext_vector_type(8))) _Float16 f16x8;       // 8 f16 = 4 VGPR (MFMA A/B frag)
typedef __attribute__((ext_vector_type(8))) short bf16x8;         // 8 bf16 = 4 VGPR
typedef __attribute__((ext_vector_type(4))) float f32x4;          // MFMA C/D frag
typedef __attribute__((ext_vector_type(8))) unsigned short ushort8;

// ---------------- dtype helpers ----------------

__device__ __forceinline__ float bf2f(unsigned short u) {
    union { unsigned int i; float f; } x; x.i = ((unsigned int)u) << 16; return x.f;
}
__device__ __forceinline__ unsigned short f2bf(float f) {
    union { float f; unsigned int i; } x; x.f = f;
    unsigned int i = x.i;
    unsigned int r = (i + 0x7FFFu + ((i >> 16) & 1u)) >> 16;   // RNE
    return (unsigned short)r;
}
__device__ __forceinline__ float h2f(unsigned short u) {
    _Float16 h; __builtin_memcpy(&h, &u, 2); return (float)h;
}
__device__ __forceinline__ unsigned short f2h(float f) {
    _Float16 h = (_Float16)f; unsigned short u; __builtin_memcpy(&u, &h, 2); return u;
}
__device__ __forceinline__ float ld1(const void* p, long i, bool bf) {
    return bf ? bf2f(((const unsigned short*)p)[i]) : ((const float*)p)[i];
}
__device__ __forceinline__ float4 ld4(const void* p, long i, bool bf) {
    if (bf) {
        ushort4 u = *(const ushort4*)((const unsigned short*)p + i);
        return make_float4(bf2f(u.x), bf2f(u.y), bf2f(u.z), bf2f(u.w));
    }
    return *(const float4*)((const float*)p + i);
}

// Detect whether float tensors are bf16-packed (see round 0 notes).
__global__ void k_detect(const unsigned int* __restrict__ x, int* __restrict__ flag) {
    int t = threadIdx.x;
    int hits = 0;
    for (int i = 0; i < 64; i++) {
        unsigned int w = x[t * 64 + i];
        unsigned int e = (w >> 7) & 0xFF;
        hits += (e >= 0x70 && e <= 0x85) ? 1 : 0;
    }
    __shared__ int sh[256];
    sh[t] = hits;
    __syncthreads();
    for (int off = 128; off; off >>= 1) {
        if (t < off) sh[t] += sh[t + off];
        __syncthreads();
    }
    if (t == 0) *flag = (sh[0] > 8192) ? 1 : 0;   // 16384 words total
}

// ---------------- weight prep: W[K][N] -> WT[Npad][K] f16 hi/lo + bf16 ----------------
// grid (K/256, Npad); rows n >= N zero-filled (lets GEMM read a full 128-tile).

__global__ void k_prep(const void* __restrict__ W, int K, int N,
                       _Float16* __restrict__ outH, _Float16* __restrict__ outL,
                       unsigned short* __restrict__ outBf, const int* __restrict__ dflag) {
    const int k = blockIdx.x * 256 + threadIdx.x;
    const int n = blockIdx.y;
    const bool bf = (*dflag != 0);
    float w = (n < N) ? ld1(W, (long)k * N + n, bf) : 0.f;
    long idx = (long)n * K + k;
    _Float16 h = (_Float16)w;
    outH[idx] = h;
    outL[idx] = (_Float16)(w - (float)h);
    outBf[idx] = f2bf(w);
}

// ---------------- CSR build (counting sort by dst) ----------------

__global__ void k_hist(const int* __restrict__ dst, int E, int* __restrict__ counts) {
    int i = blockIdx.x * blockDim.x + threadIdx.x;
    if (i < E) atomicAdd(&counts[dst[i]], 1);
}

__global__ void k_scan_a(const int* __restrict__ counts, int N,
                         int* __restrict__ ex, int* __restrict__ bsums) {
    __shared__ int s[256];
    int t = threadIdx.x;
    int base = blockIdx.x * 1024;
    int v[4]; int sum = 0;
    #pragma unroll
    for (int j = 0; j < 4; j++) {
        int idx = base + t * 4 + j;
        v[j] = (idx < N) ? counts[idx] : 0;
        sum += v[j];
    }
    s[t] = sum;
    __syncthreads();
    for (int off = 1; off < 256; off <<= 1) {
        int x = (t >= off) ? s[t - off] : 0;
        __syncthreads();
        s[t] += x;
        __syncthreads();
    }
    int run = (t > 0) ? s[t - 1] : 0;
    #pragma unroll
    for (int j = 0; j < 4; j++) {
        int idx = base + t * 4 + j;
        if (idx < N) ex[idx] = run;
        run += v[j];
    }
    if (t == 255) bsums[blockIdx.x] = s[255];
}

__global__ void k_scan_b(int* __restrict__ bsums, int nb) {
    __shared__ int s[256];
    int t = threadIdx.x;
    s[t] = (t < nb) ? bsums[t] : 0;
    __syncthreads();
    for (int off = 1; off < 256; off <<= 1) {
        int x = (t >= off) ? s[t - off] : 0;
        __syncthreads();
        s[t] += x;
        __syncthreads();
    }
    if (t < nb) bsums[t] = (t > 0) ? s[t - 1] : 0;
}

__global__ void k_scan_c(const int* __restrict__ ex, const int* __restrict__ bsums,
                         int N, int E, int* __restrict__ row_ptr) {
    int i = blockIdx.x * blockDim.x + threadIdx.x;
    if (i < N) row_ptr[i] = ex[i] + bsums[i >> 10];
    if (i == 0) row_ptr[N] = E;
}

__global__ void k_scatter(const int* __restrict__ src, const int* __restrict__ dst,
                          const void* __restrict__ ewin, const int* __restrict__ dflag,
                          const int* __restrict__ row_ptr, int* __restrict__ cursor,
                          int E, int* __restrict__ es, float* __restrict__ ew) {
    int i = blockIdx.x * blockDim.x + threadIdx.x;
    if (i >= E) return;
    bool bf = (*dflag != 0);
    int d = dst[i];
    int p = row_ptr[d] + atomicAdd(&cursor[d], 1);
    es[p] = src[i];
    ew[p] = ld1(ewin, i, bf);
}

// ---------------- MFMA GEMM: C = act(A[M,K] @ W[K,N] (+ bias)) ----------------
// 128x128 tile, 256 threads (4 waves, 2x2), BK=32. Weights PRE-TRANSPOSED
// ([Npad][K] f16 hi/lo + bf16 planes from k_prep).
// SINGLE K-sweep (round-3 structure): per k0, ALL needed planes are staged
// ONCE (A hi+lo if fp32; Bh + Bl if fp32 weights) with the same conflict-free
// raw-copy pattern (thread t -> row t>>1, k-half (t&1)*16, 2x 16B), then all
// MFMA groups run on the resident tiles:
//   G1: a_hi x b_hi (always)   G2: a_lo x b_hi (fp32 A)   G3: a_hi x b_lo (fp32 wts)
// (round-5 lesson: re-sweeping K per pass re-fetches A 2-3x -> 599 MB FETCH;
//  round-4 lesson: B direct-from-global per K-step is latency-bound.)
// a_mode==1 (raw bf16 A): bf16 MFMA against the bf16 weight plane, 1 group.
// Operand-swapped MFMA: acc[i][j] = mfma(b[j], a[i], acc) -> D^T layout:
//   m = m0+wm+i*16+(lane&15), n = n0+wn+j*16+(lane>>4)*4+reg
// -> each lane stores 4 consecutive n (8B f16 / 16B fp32), coalesced.

__global__ __launch_bounds__(256) void k_gemm(
    const void* __restrict__ A,
    const _Float16* __restrict__ BTh, const _Float16* __restrict__ BTl,
    const unsigned short* __restrict__ BTbf,
    const void* __restrict__ bias, void* __restrict__ C, int M, int K, int N,
    int a_kind, int c_mode, int act, const int* __restrict__ dflag)
{
    const bool inbf = (*dflag != 0);
    const int  a_mode = (a_kind == 2) ? 2 : (inbf ? 1 : 0);   // 0 fp32, 1 bf16 raw, 2 f16
    const bool a_lo = (a_mode == 0);
    const bool b_lo = !inbf;

    // [row][k], k contiguous; pad 32->40 elems: 16-row-strided b128 frag reads
    // land on balanced bank quads (8 words/bank = minimum, conflict-free).
    __shared__ unsigned short Ah[128][40];
    __shared__ unsigned short Al[128][40];
    __shared__ unsigned short Bh[128][40];
    __shared__ unsigned short Bl[128][40];

    const int t  = threadIdx.x;
    const int m0 = blockIdx.y * 128;        // grid: x = n-tiles (fast) -> A-panel L2 reuse
    const int n0 = blockIdx.x * 128;

    const int lane = t & 63;
    const int wv   = t >> 6;
    const int wm   = (wv & 1) * 64;         // wave's 64x64 quadrant
    const int wn   = (wv >> 1) * 64;
    const int lr   = lane & 15;             // frag index (m for A, n for B)
    const int lk   = (lane >> 4) * 8;       // frag k-offset (8 elems = b128)

    f32x4 acc[4][4];
    const f32x4 vzero = {0.f, 0.f, 0.f, 0.f};
    #pragma unroll
    for (int i = 0; i < 4; i++)
        #pragma unroll
        for (int j = 0; j < 4; j++) acc[i][j] = vzero;

    // staging map: thread -> (row = t>>1, k-half = (t&1)*16), 2x 16B per plane
    const int  ar  = t >> 1;
    const int  ak  = (t & 1) * 16;
    const long agm = (long)(m0 + ar);
    const long brow = (long)(n0 + ar) * K;  // B staging source row (pre-transposed)
    const unsigned short* Bsrc = (a_mode == 1) ? BTbf : (const unsigned short*)BTh;

    for (int k0 = 0; k0 < K; k0 += 32) {
        // ---- stage all needed planes for this k0 (once) ----
        #pragma unroll
        for (int c = 0; c < 2; c++) {
            long abase = agm * K + k0 + ak + c * 8;
            if (a_mode != 0) {              // raw 16B copy (f16 or bf16 bits)
                uint4 raw = make_uint4(0, 0, 0, 0);
                if (agm < M) raw = *(const uint4*)((const unsigned short*)A + abase);
                *(uint4*)&Ah[ar][ak + c * 8] = raw;
            } else {                        // fp32 -> exact f16 hi + lo
                float4 v0 = make_float4(0.f, 0.f, 0.f, 0.f), v1 = v0;
                if (agm < M) {
                    v0 = *(const float4*)((const float*)A + abase);
                    v1 = *(const float4*)((const float*)A + abase + 4);
                }
                float f[8] = {v0.x, v0.y, v0.z, v0.w, v1.x, v1.y, v1.z, v1.w};
                union { _Float16 h[8]; uint4 q; } H, L;
                #pragma unroll
                for (int e = 0; e < 8; e++) {
                    _Float16 hh = (_Float16)f[e];
                    H.h[e] = hh;
                    L.h[e] = (_Float16)(f[e] - (float)hh);
                }
                *(uint4*)&Ah[ar][ak + c * 8] = H.q;
                *(uint4*)&Al[ar][ak + c * 8] = L.q;
            }
            *(uint4*)&Bh[ar][ak + c * 8] = *(const uint4*)&Bsrc[brow + k0 + ak + c * 8];
            if (b_lo)
                *(uint4*)&Bl[ar][ak + c * 8] =
                    *(const uint4*)&((const unsigned short*)BTl)[brow + k0 + ak + c * 8];
        }
        __syncthreads();

        if (a_mode == 1) {
            bf16x8 a[4], b[4];
            #pragma unroll
            for (int f = 0; f < 4; f++) {
                a[f] = *(const bf16x8*)&Ah[wm + f * 16 + lr][lk];
                b[f] = *(const bf16x8*)&Bh[wn + f * 16 + lr][lk];
            }
            #pragma unroll
            for (int i = 0; i < 4; i++)
                #pragma unroll
                for (int j = 0; j < 4; j++)
                    acc[i][j] = __builtin_amdgcn_mfma_f32_16x16x32_bf16(b[j], a[i], acc[i][j], 0, 0, 0);
        } else {
            f16x8 a[4], b[4];
            #pragma unroll
            for (int f = 0; f < 4; f++) {
                a[f] = *(const f16x8*)&Ah[wm + f * 16 + lr][lk];
                b[f] = *(const f16x8*)&Bh[wn + f * 16 + lr][lk];
            }
            #pragma unroll
            for (int i = 0; i < 4; i++)
                #pragma unroll
                for (int j = 0; j < 4; j++)
                    acc[i][j] = __builtin_amdgcn_mfma_f32_16x16x32_f16(b[j], a[i], acc[i][j], 0, 0, 0);
            if (a_lo) {                      // G2: a_lo x b_hi
                f16x8 al[4];
                #pragma unroll
                for (int f = 0; f < 4; f++) al[f] = *(const f16x8*)&Al[wm + f * 16 + lr][lk];
                #pragma unroll
                for (int i = 0; i < 4; i++)
                    #pragma unroll
                    for (int j = 0; j < 4; j++)
                        acc[i][j] = __builtin_amdgcn_mfma_f32_16x16x32_f16(b[j], al[i], acc[i][j], 0, 0, 0);
            }
            if (b_lo) {                      // G3: a_hi x b_lo
                f16x8 bl[4];
                #pragma unroll
                for (int f = 0; f < 4; f++) bl[f] = *(const f16x8*)&Bl[wn + f * 16 + lr][lk];
                #pragma unroll
                for (int i = 0; i < 4; i++)
                    #pragma unroll
                    for (int j = 0; j < 4; j++)
                        acc[i][j] = __builtin_amdgcn_mfma_f32_16x16x32_f16(bl[j], a[i], acc[i][j], 0, 0, 0);
            }
        }
        __syncthreads();
    }

    // ---- epilogue (swapped D layout): lane owns 4 consecutive n per m-row ----
    const bool has_bias = (bias != nullptr);
    const int  nb4 = (lane >> 4) * 4;
    #pragma unroll
    for (int i = 0; i < 4; i++) {
        int m = m0 + wm + i * 16 + lr;
        if (m >= M) continue;
        #pragma unroll
        for (int j = 0; j < 4; j++) {
            int nb = n0 + wn + j * 16 + nb4;
            if (nb >= N) continue;          // N % 4 == 0 always
            float4 bv = has_bias ? ld4(bias, nb, inbf) : make_float4(0.f, 0.f, 0.f, 0.f);
            float v0 = acc[i][j][0] + bv.x;
            float v1 = acc[i][j][1] + bv.y;
            float v2 = acc[i][j][2] + bv.z;
            float v3 = acc[i][j][3] + bv.w;
            if (act) {
                v0 = fmaxf(v0, 0.f); v1 = fmaxf(v1, 0.f);
                v2 = fmaxf(v2, 0.f); v3 = fmaxf(v3, 0.f);
            }
            if (c_mode == 2) {
                ushort4 o; o.x = f2h(v0); o.y = f2h(v1); o.z = f2h(v2); o.w = f2h(v3);
                *(ushort4*)&((unsigned short*)C)[(long)m * N + nb] = o;
            } else {
                *(float4*)&((float*)C)[(long)m * N + nb] = make_float4(v0, v1, v2, v3);
            }
        }
    }
}

// ---------------- SPMM: out[d] = act(sum_e w[e]*sup[src[e]] + bias), F=256 ----------------
// One wave per dst node, split into two 32-lane halves, each half owns a
// different edge per iteration; lane (l&31) owns 8 feats (16B ushort8 load).

__global__ __launch_bounds__(256) void k_spmm(
    const unsigned short* __restrict__ sup, const int* __restrict__ es,
    const float* __restrict__ ew, const int* __restrict__ row_ptr,
    const void* __restrict__ bias, unsigned short* __restrict__ out,
    int Nn, int act, const int* __restrict__ dflag)
{
    const int wave = threadIdx.x >> 6;
    const int lane = threadIdx.x & 63;
    const int node = blockIdx.x * 4 + wave;
    if (node >= Nn) return;
    const bool bf = (*dflag != 0);

    const int half = lane >> 5;          // 0 or 1
    const int fl   = (lane & 31) * 8;    // feature base (8 f16 = 16 B)

    const int e0 = row_ptr[node], e1 = row_ptr[node + 1];
    float acc[8] = {};

    #pragma unroll 4
    for (int e = e0 + half; e < e1; e += 2) {
        int s = es[e];
        float w = ew[e];
        ushort8 u = *(const ushort8*)&sup[(long)s * 256 + fl];
        #pragma unroll
        for (int i = 0; i < 8; i++) acc[i] += w * h2f(u[i]);
    }

    #pragma unroll
    for (int i = 0; i < 8; i++) acc[i] += __shfl_xor(acc[i], 32, 64);

    if (half == 0) {
        float4 b0 = ld4(bias, fl, bf);
        float4 b1 = ld4(bias, fl + 4, bf);
        float bb[8] = {b0.x, b0.y, b0.z, b0.w, b1.x, b1.y, b1.z, b1.w};
        ushort8 o;
        #pragma unroll
        for (int i = 0; i < 8; i++) {
            float v = acc[i] + bb[i];
            if (act) v = fmaxf(v, 0.f);
            o[i] = f2h(v);
        }
        *(ushort8*)&out[(long)node * 256 + fl] = o;
    }
}

// ---------------- softmax over NC classes, one wave per row ----------------

__global__ __launch_bounds__(256) void k_softmax(
    const float* __restrict__ logits, void* __restrict__ out, int M, int NC,
    const int* __restrict__ dflag)
{
    const int wave = threadIdx.x >> 6;
    const int lane = threadIdx.x & 63;
    const int row = blockIdx.x * 4 + wave;
    if (row >= M) return;
    const bool bf = (*dflag != 0);

    float v = (lane < NC) ? logits[(long)row * NC + lane] : -INFINITY;
    float m = v;
    #pragma unroll
    for (int off = 32; off; off >>= 1) m = fmaxf(m, __shfl_xor(m, off, 64));
    float p = (lane < NC) ? expf(v - m) : 0.f;
    float s = p;
    #pragma unroll
    for (int off = 32; off; off >>= 1) s += __shfl_xor(s, off, 64);
    if (lane < NC) {
        float r = p / s;
        if (bf) ((unsigned short*)out)[(long)row * NC + lane] = f2bf(r);
        else    ((float*)out)[(long)row * NC + lane] = r;
    }
}

// ---------------- orchestration ----------------

extern "C" void kernel_launch(void* const* d_in, const int* in_sizes, int n_in,
                              void* d_out, int out_size, void* d_ws, size_t ws_size,
                              hipStream_t stream) {
    const void* x    = d_in[0];
    const int*  esrc = (const int*)d_in[1];
    const int*  edst = (const int*)d_in[2];
    const void* ewin = d_in[3];
    const void* w1 = d_in[4],  *b1 = d_in[5];
    const void* w2 = d_in[6],  *b2 = d_in[7];
    const void* wc1 = d_in[8], *bc1 = d_in[9];
    const void* wc2 = d_in[10], *bc2 = d_in[11];
    const void* wc3 = d_in[12], *bc3 = d_in[13];
    const void* wc4 = d_in[14], *bc4 = d_in[15];

    const int HID  = in_sizes[5];                 // 256
    const int IND  = in_sizes[4] / HID;           // 512
    const int HID2 = in_sizes[9];                 // 512
    const int NC   = in_sizes[15];                // 40
    const int M    = in_sizes[0] / IND;           // 100000
    const int E    = in_sizes[1];                 // 3200000

    char* ws = (char*)d_ws;
    int* dflag = (int*)ws;                                        // 256 B slot
    unsigned short* bufA = (unsigned short*)(ws + 256);           // sup (f16, 51.2 MB used)
    unsigned short* bufB = (unsigned short*)(ws + 256 + 102400000L);  // h1/h2 (f16)
    char*  wsC  = ws + 256 + 204800000L;                          // h3/h5 (f16) / CSR
    char*  wsD  = wsC + 204800000L;                               // h4 (f16) + WT tail
    unsigned short* bufC = (unsigned short*)wsC;
    unsigned short* bufD = (unsigned short*)wsD;

    // CSR arrays live inside bufC's region (dead before the MLP starts)
    int* counts  = (int*)wsC;
    int* row_ptr = counts + 100352;
    int* cursor  = row_ptr + 100352;
    int* bsums   = cursor + 100352;
    int* ex      = bsums + 1024;
    int* es      = ex + 100352;
    float* ewS   = (float*)(es + E);

    float* logits = (float*)bufA;   // reuse after support2 is dead (16 MB)

    // pre-transposed weight planes live in the tail of the h4 region
    // (h4 f16 uses only the first 102.4 MB of the 204.8 MB slot)
    _Float16* P = (_Float16*)(wsD + 103000000L);
    // per matrix: [H plane][L plane][Bf plane], each Npad*K elems (2 B each)
    const long s_w1 = 256L * 512, s_w2 = 256L * 256, s_c1 = 512L * 256;
    const long s_c2 = 512L * 512, s_c3 = 512L * 512, s_c4 = 128L * 512;
    _Float16 *w1h = P,              *w1l = w1h + s_w1; unsigned short* w1b = (unsigned short*)(w1l + s_w1);
    _Float16 *w2h = (_Float16*)(w1b + s_w1), *w2l = w2h + s_w2; unsigned short* w2b = (unsigned short*)(w2l + s_w2);
    _Float16 *c1h = (_Float16*)(w2b + s_w2), *c1l = c1h + s_c1; unsigned short* c1b = (unsigned short*)(c1l + s_c1);
    _Float16 *c2h = (_Float16*)(c1b + s_c1), *c2l = c2h + s_c2; unsigned short* c2b = (unsigned short*)(c2l + s_c2);
    _Float16 *c3h = (_Float16*)(c2b + s_c2), *c3l = c3h + s_c3; unsigned short* c3b = (unsigned short*)(c3l + s_c3);
    _Float16 *c4h = (_Float16*)(c3b + s_c3), *c4l = c4h + s_c4; unsigned short* c4b = (unsigned short*)(c4l + s_c4);

    // 0. dtype sniff
    k_detect<<<1, 256, 0, stream>>>((const unsigned int*)x, dflag);

    // 0b. weight prep (transpose + f16 hi/lo + bf16), all tiny
    k_prep<<<dim3(IND / 256, HID),  256, 0, stream>>>(w1,  IND,  HID,  w1h, w1l, w1b, dflag);
    k_prep<<<dim3(HID / 256, HID),  256, 0, stream>>>(w2,  HID,  HID,  w2h, w2l, w2b, dflag);
    k_prep<<<dim3(HID / 256, HID2), 256, 0, stream>>>(wc1, HID,  HID2, c1h, c1l, c1b, dflag);
    k_prep<<<dim3(HID2 / 256, HID2),256, 0, stream>>>(wc2, HID2, HID2, c2h, c2l, c2b, dflag);
    k_prep<<<dim3(HID2 / 256, HID2),256, 0, stream>>>(wc3, HID2, HID2, c3h, c3l, c3b, dflag);
    k_prep<<<dim3(HID2 / 256, 128), 256, 0, stream>>>(wc4, HID2, NC,   c4h, c4l, c4b, dflag);

    // 1. CSR build
    hipMemsetAsync(counts, 0, 100352 * sizeof(int), stream);
    hipMemsetAsync(cursor, 0, 100352 * sizeof(int), stream);
    k_hist<<<(E + 255) / 256, 256, 0, stream>>>(edst, E, counts);
    int nb = (M + 1023) / 1024;                                   // 98
    k_scan_a<<<nb, 256, 0, stream>>>(counts, M, ex, bsums);
    k_scan_b<<<1, 256, 0, stream>>>(bsums, nb);
    k_scan_c<<<(M + 255) / 256, 256, 0, stream>>>(ex, bsums, M, E, row_ptr);
    k_scatter<<<(E + 255) / 256, 256, 0, stream>>>(esrc, edst, ewin, dflag, row_ptr, cursor, E, es, ewS);

    const int gm128 = (M + 127) / 128;   // 782
    dim3 blk(256);

    // 2. support1 = x @ w1                      [M,512]@[512,256] -> bufA (f16)
    k_gemm<<<dim3(HID / 128, gm128), blk, 0, stream>>>(x, w1h, w1l, w1b, nullptr, bufA, M, IND, HID, 0, 2, 0, dflag);
    // 3. h1 = relu(spmm(support1) + b1)        -> bufB (f16)
    k_spmm<<<(M + 3) / 4, blk, 0, stream>>>(bufA, es, ewS, row_ptr, b1, bufB, M, 1, dflag);
    // 4. support2 = h1 @ w2                    -> bufA (f16)
    k_gemm<<<dim3(HID / 128, gm128), blk, 0, stream>>>(bufB, w2h, w2l, w2b, nullptr, bufA, M, HID, HID, 2, 2, 0, dflag);
    // 5. h2 = spmm(support2) + b2              -> bufB (f16)
    k_spmm<<<(M + 3) / 4, blk, 0, stream>>>(bufA, es, ewS, row_ptr, b2, bufB, M, 0, dflag);
    // 6. h3 = relu(h2 @ wc1 + bc1)             [M,256]@[256,512] -> bufC (f16, CSR now dead)
    k_gemm<<<dim3(HID2 / 128, gm128), blk, 0, stream>>>(bufB, c1h, c1l, c1b, bc1, bufC, M, HID, HID2, 2, 2, 1, dflag);
    // 7. h4 = relu(h3 @ wc2 + bc2)             -> bufD (f16)
    k_gemm<<<dim3(HID2 / 128, gm128), blk, 0, stream>>>(bufC, c2h, c2l, c2b, bc2, bufD, M, HID2, HID2, 2, 2, 1, dflag);
    // 8. h5 = relu(h4 @ wc3 + bc3)             -> bufC (f16)
    k_gemm<<<dim3(HID2 / 128, gm128), blk, 0, stream>>>(bufD, c3h, c3l, c3b, bc3, bufC, M, HID2, HID2, 2, 2, 1, dflag);
    // 9. logits = h5 @ wc4 + bc4               [M,512]@[512,40] -> bufA (fp32)
    k_gemm<<<dim3(1, gm128), blk, 0, stream>>>(bufC, c4h, c4l, c4b, bc4, logits, M, HID2, NC, 2, 0, 0, dflag);
    // 10. softmax -> d_out
    k_softmax<<<(M + 3) / 4, blk, 0, stream>>>(logits, d_out, M, NC, dflag);
}

// Round 7
// 1755.207 us; speedup vs baseline: 1.4500x; 1.2243x over previous
//
#include <hip/hip_runtime.h>
#include <math.h>

typedef __attribute__((ext_vector_type(8))) _Float16 f16x8;       // 8 f16 = 4 VGPR (MFMA A/B frag)
typedef __attribute__((ext_vector_type(8))) short bf16x8;         // 8 bf16 = 4 VGPR
typedef __attribute__((ext_vector_type(4))) float f32x4;          // MFMA C/D frag
typedef __attribute__((ext_vector_type(8))) unsigned short ushort8;

// ---------------- dtype helpers ----------------

__device__ __forceinline__ float bf2f(unsigned short u) {
    union { unsigned int i; float f; } x; x.i = ((unsigned int)u) << 16; return x.f;
}
__device__ __forceinline__ unsigned short f2bf(float f) {
    union { float f; unsigned int i; } x; x.f = f;
    unsigned int i = x.i;
    unsigned int r = (i + 0x7FFFu + ((i >> 16) & 1u)) >> 16;   // RNE
    return (unsigned short)r;
}
__device__ __forceinline__ float h2f(unsigned short u) {
    _Float16 h; __builtin_memcpy(&h, &u, 2); return (float)h;
}
__device__ __forceinline__ unsigned short f2h(float f) {
    _Float16 h = (_Float16)f; unsigned short u; __builtin_memcpy(&u, &h, 2); return u;
}
__device__ __forceinline__ float ld1(const void* p, long i, bool bf) {
    return bf ? bf2f(((const unsigned short*)p)[i]) : ((const float*)p)[i];
}
__device__ __forceinline__ float4 ld4(const void* p, long i, bool bf) {
    if (bf) {
        ushort4 u = *(const ushort4*)((const unsigned short*)p + i);
        return make_float4(bf2f(u.x), bf2f(u.y), bf2f(u.z), bf2f(u.w));
    }
    return *(const float4*)((const float*)p + i);
}

// async global->LDS DMA, 16B/lane. LDS dest = wave-uniform base + lane*16.
typedef __attribute__((address_space(3))) unsigned int lds_u32;
typedef __attribute__((address_space(1))) unsigned int glb_u32;
__device__ __forceinline__ void gload16(const void* g, void* l) {
    __builtin_amdgcn_global_load_lds((const glb_u32*)g, (lds_u32*)l, 16, 0, 0);
}

// Detect whether float tensors are bf16-packed (see round 0 notes).
__global__ void k_detect(const unsigned int* __restrict__ x, int* __restrict__ flag) {
    int t = threadIdx.x;
    int hits = 0;
    for (int i = 0; i < 64; i++) {
        unsigned int w = x[t * 64 + i];
        unsigned int e = (w >> 7) & 0xFF;
        hits += (e >= 0x70 && e <= 0x85) ? 1 : 0;
    }
    __shared__ int sh[256];
    sh[t] = hits;
    __syncthreads();
    for (int off = 128; off; off >>= 1) {
        if (t < off) sh[t] += sh[t + off];
        __syncthreads();
    }
    if (t == 0) *flag = (sh[0] > 8192) ? 1 : 0;   // 16384 words total
}

// ---------------- weight prep: W[K][N] -> WT[Npad][K] f16 hi/lo + bf16 ----------------

__global__ void k_prep(const void* __restrict__ W, int K, int N,
                       _Float16* __restrict__ outH, _Float16* __restrict__ outL,
                       unsigned short* __restrict__ outBf, const int* __restrict__ dflag) {
    const int k = blockIdx.x * 256 + threadIdx.x;
    const int n = blockIdx.y;
    const bool bf = (*dflag != 0);
    float w = (n < N) ? ld1(W, (long)k * N + n, bf) : 0.f;
    long idx = (long)n * K + k;
    _Float16 h = (_Float16)w;
    outH[idx] = h;
    outL[idx] = (_Float16)(w - (float)h);
    outBf[idx] = f2bf(w);
}

// ---------------- CSR build (counting sort by dst) ----------------

__global__ void k_hist(const int* __restrict__ dst, int E, int* __restrict__ counts) {
    int i = blockIdx.x * blockDim.x + threadIdx.x;
    if (i < E) atomicAdd(&counts[dst[i]], 1);
}

__global__ void k_scan_a(const int* __restrict__ counts, int N,
                         int* __restrict__ ex, int* __restrict__ bsums) {
    __shared__ int s[256];
    int t = threadIdx.x;
    int base = blockIdx.x * 1024;
    int v[4]; int sum = 0;
    #pragma unroll
    for (int j = 0; j < 4; j++) {
        int idx = base + t * 4 + j;
        v[j] = (idx < N) ? counts[idx] : 0;
        sum += v[j];
    }
    s[t] = sum;
    __syncthreads();
    for (int off = 1; off < 256; off <<= 1) {
        int x = (t >= off) ? s[t - off] : 0;
        __syncthreads();
        s[t] += x;
        __syncthreads();
    }
    int run = (t > 0) ? s[t - 1] : 0;
    #pragma unroll
    for (int j = 0; j < 4; j++) {
        int idx = base + t * 4 + j;
        if (idx < N) ex[idx] = run;
        run += v[j];
    }
    if (t == 255) bsums[blockIdx.x] = s[255];
}

__global__ void k_scan_b(int* __restrict__ bsums, int nb) {
    __shared__ int s[256];
    int t = threadIdx.x;
    s[t] = (t < nb) ? bsums[t] : 0;
    __syncthreads();
    for (int off = 1; off < 256; off <<= 1) {
        int x = (t >= off) ? s[t - off] : 0;
        __syncthreads();
        s[t] += x;
        __syncthreads();
    }
    if (t < nb) bsums[t] = (t > 0) ? s[t - 1] : 0;
}

__global__ void k_scan_c(const int* __restrict__ ex, const int* __restrict__ bsums,
                         int N, int E, int* __restrict__ row_ptr) {
    int i = blockIdx.x * blockDim.x + threadIdx.x;
    if (i < N) row_ptr[i] = ex[i] + bsums[i >> 10];
    if (i == 0) row_ptr[N] = E;
}

__global__ void k_scatter(const int* __restrict__ src, const int* __restrict__ dst,
                          const void* __restrict__ ewin, const int* __restrict__ dflag,
                          const int* __restrict__ row_ptr, int* __restrict__ cursor,
                          int E, int* __restrict__ es, float* __restrict__ ew) {
    int i = blockIdx.x * blockDim.x + threadIdx.x;
    if (i >= E) return;
    bool bf = (*dflag != 0);
    int d = dst[i];
    int p = row_ptr[d] + atomicAdd(&cursor[d], 1);
    es[p] = src[i];
    ew[p] = ld1(ewin, i, bf);
}

// ---------------- MFMA GEMM: C = act(A[M,K] @ W[K,N] (+ bias)) ----------------
// 128x128 tile, 256 threads (4 waves 2x2), BK=32, DOUBLE-BUFFERED 2-PHASE:
// per K-step: {issue global_load_lds of tile t+1 into buf^1} || {ds_read+MFMA
// on buf} -> ONE __syncthreads() (drains vmcnt+lgkm). Staging latency hides
// under compute (round-6 lesson: serial stage->barrier->compute left all
// pipes at ~15%).
// Raw planes (A-f16/bf16, Bh, Bl) staged via global_load_lds (16B/lane DMA,
// linear [128][32] LDS rows; dest chunk = wave-uniform base + lane*16;
// source row = chunk*16 + lane>>2, col = (lane&3)*8).
// GEMM1 (fp32 A): A loads issued ONE ITERATION AHEAD into 16 VGPRs (T14
// split), f16 hi/lo convert + ds_write just before the barrier.
// MFMA groups on resident tiles: G1 a*bh; G2 a_lo*bh (fp32 A); G3 a*bl
// (fp32 weights). a_mode==1 (raw bf16 A): single bf16 group vs bf16 plane.
// Operand-swapped MFMA -> D^T layout -> coalesced 8B/16B C stores.

template<int AK>   // 0 = A is the input tensor (fp32 or raw-bf16); 2 = f16 intermediate
__global__ __launch_bounds__(256) void k_gemm(
    const void* __restrict__ A,
    const _Float16* __restrict__ BTh, const _Float16* __restrict__ BTl,
    const unsigned short* __restrict__ BTbf,
    const void* __restrict__ bias, void* __restrict__ C, int M, int K, int N,
    int c_mode, int act, const int* __restrict__ dflag)
{
    const bool inbf = (*dflag != 0);
    const int  a_mode = (AK == 2) ? 2 : (inbf ? 1 : 0);   // 0 fp32, 1 bf16 raw, 2 f16
    const bool rega = (a_mode == 0);
    const bool b_lo = !inbf;

    constexpr int NPL = (AK == 0) ? 4 : 3;
    constexpr int PAH = 0, PBH = 1, PBL = 2;
    constexpr int PAL = (AK == 0) ? 3 : 2;     // only touched when rega
    __shared__ unsigned short Lds[2][NPL][128][32];

    const int t  = threadIdx.x;
    const int m0 = blockIdx.y * 128;    // grid: x = n-tiles (fast) -> A-panel L2 reuse
    const int n0 = blockIdx.x * 128;

    const int lane = t & 63;
    const int wv   = t >> 6;
    const int wm   = (wv & 1) * 64;
    const int wn   = (wv >> 1) * 64;
    const int lr   = lane & 15;
    const int lk   = (lane >> 4) * 8;

    f32x4 acc[4][4];
    const f32x4 vzero = {0.f, 0.f, 0.f, 0.f};
    #pragma unroll
    for (int i = 0; i < 4; i++)
        #pragma unroll
        for (int j = 0; j < 4; j++) acc[i][j] = vzero;

    // gload map: chunk c of this wave covers rows (wv*2+c)*16 .. +15
    const int srow = lane >> 2;
    const int scol = (lane & 3) * 8;
    const unsigned short* Bh16 = (a_mode == 1) ? BTbf : (const unsigned short*)BTh;
    const unsigned short* Bl16 = (const unsigned short*)BTl;
    const unsigned short* A16  = (const unsigned short*)A;
    const float* A32 = (const float*)A;

    // reg-staged A map (fp32 path): thread -> row t>>1, k-cols (t&1)*16..+15
    const int  ar = t >> 1;
    const int  ak = (t & 1) * 16;
    long arow = (long)(m0 + ar); if (arow >= M) arow = M - 1;

    float fr[16];
    const int nt = K / 32;

    auto STAGE_GL = [&](int buf, int k0) {
        #pragma unroll
        for (int c = 0; c < 2; c++) {
            const int r = (wv * 2 + c) * 16;
            long bro = (long)(n0 + r + srow) * K + k0 + scol;
            gload16(Bh16 + bro, (void*)&Lds[buf][PBH][r][0]);
            if (b_lo && a_mode != 1)
                gload16(Bl16 + bro, (void*)&Lds[buf][PBL][r][0]);
            if (!rega) {
                long gr = (long)(m0 + r + srow); if (gr >= M) gr = M - 1;
                gload16(A16 + gr * K + k0 + scol, (void*)&Lds[buf][PAH][r][0]);
            }
        }
    };
    auto A_LOAD = [&](int k0) {
        long base = arow * K + k0 + ak;
        #pragma unroll
        for (int j = 0; j < 4; j++) {
            float4 v = *(const float4*)(A32 + base + j * 4);
            fr[j*4+0] = v.x; fr[j*4+1] = v.y; fr[j*4+2] = v.z; fr[j*4+3] = v.w;
        }
    };
    auto A_WRITE = [&](int buf) {
        if constexpr (AK == 0) {
            #pragma unroll
            for (int c = 0; c < 2; c++) {
                union { _Float16 h[8]; uint4 q; } H, L2;
                #pragma unroll
                for (int e = 0; e < 8; e++) {
                    float f = fr[c * 8 + e];
                    _Float16 hh = (_Float16)f;
                    H.h[e]  = hh;
                    L2.h[e] = (_Float16)(f - (float)hh);
                }
                *(uint4*)&Lds[buf][PAH][ar][ak + c * 8] = H.q;
                *(uint4*)&Lds[buf][PAL][ar][ak + c * 8] = L2.q;
            }
        }
    };

    // prologue: stage tile 0, prefetch fp32 A regs for tile 1
    if (rega) A_LOAD(0);
    STAGE_GL(0, 0);
    if (rega) { A_WRITE(0); if (nt > 1) A_LOAD(32); }
    __syncthreads();

    for (int ti = 0; ti < nt; ti++) {
        const int cur = ti & 1, nxt = cur ^ 1;
        if (ti + 1 < nt) {
            STAGE_GL(nxt, (ti + 1) * 32);
            if (rega) { A_WRITE(nxt); if (ti + 2 < nt) A_LOAD((ti + 2) * 32); }
        }

        if (a_mode == 1) {
            bf16x8 a[4], b[4];
            #pragma unroll
            for (int f = 0; f < 4; f++) {
                a[f] = *(const bf16x8*)&Lds[cur][PAH][wm + f * 16 + lr][lk];
                b[f] = *(const bf16x8*)&Lds[cur][PBH][wn + f * 16 + lr][lk];
            }
            #pragma unroll
            for (int i = 0; i < 4; i++)
                #pragma unroll
                for (int j = 0; j < 4; j++)
                    acc[i][j] = __builtin_amdgcn_mfma_f32_16x16x32_bf16(b[j], a[i], acc[i][j], 0, 0, 0);
        } else {
            f16x8 a[4], b[4];
            #pragma unroll
            for (int f = 0; f < 4; f++) {
                a[f] = *(const f16x8*)&Lds[cur][PAH][wm + f * 16 + lr][lk];
                b[f] = *(const f16x8*)&Lds[cur][PBH][wn + f * 16 + lr][lk];
            }
            #pragma unroll
            for (int i = 0; i < 4; i++)
                #pragma unroll
                for (int j = 0; j < 4; j++)
                    acc[i][j] = __builtin_amdgcn_mfma_f32_16x16x32_f16(b[j], a[i], acc[i][j], 0, 0, 0);
            if (rega) {                    // G2: a_lo x b_hi
                f16x8 al[4];
                #pragma unroll
                for (int f = 0; f < 4; f++)
                    al[f] = *(const f16x8*)&Lds[cur][PAL][wm + f * 16 + lr][lk];
                #pragma unroll
                for (int i = 0; i < 4; i++)
                    #pragma unroll
                    for (int j = 0; j < 4; j++)
                        acc[i][j] = __builtin_amdgcn_mfma_f32_16x16x32_f16(b[j], al[i], acc[i][j], 0, 0, 0);
            }
            if (b_lo) {                    // G3: a_hi x b_lo
                f16x8 bl[4];
                #pragma unroll
                for (int f = 0; f < 4; f++)
                    bl[f] = *(const f16x8*)&Lds[cur][PBL][wn + f * 16 + lr][lk];
                #pragma unroll
                for (int i = 0; i < 4; i++)
                    #pragma unroll
                    for (int j = 0; j < 4; j++)
                        acc[i][j] = __builtin_amdgcn_mfma_f32_16x16x32_f16(bl[j], a[i], acc[i][j], 0, 0, 0);
            }
        }
        __syncthreads();
    }

    // ---- epilogue (swapped D layout): lane owns 4 consecutive n per m-row ----
    const bool has_bias = (bias != nullptr);
    const int  nb4 = (lane >> 4) * 4;
    #pragma unroll
    for (int i = 0; i < 4; i++) {
        int m = m0 + wm + i * 16 + lr;
        if (m >= M) continue;
        #pragma unroll
        for (int j = 0; j < 4; j++) {
            int nb = n0 + wn + j * 16 + nb4;
            if (nb >= N) continue;          // N % 4 == 0 always
            float4 bv = has_bias ? ld4(bias, nb, inbf) : make_float4(0.f, 0.f, 0.f, 0.f);
            float v0 = acc[i][j][0] + bv.x;
            float v1 = acc[i][j][1] + bv.y;
            float v2 = acc[i][j][2] + bv.z;
            float v3 = acc[i][j][3] + bv.w;
            if (act) {
                v0 = fmaxf(v0, 0.f); v1 = fmaxf(v1, 0.f);
                v2 = fmaxf(v2, 0.f); v3 = fmaxf(v3, 0.f);
            }
            if (c_mode == 2) {
                ushort4 o; o.x = f2h(v0); o.y = f2h(v1); o.z = f2h(v2); o.w = f2h(v3);
                *(ushort4*)&((unsigned short*)C)[(long)m * N + nb] = o;
            } else {
                *(float4*)&((float*)C)[(long)m * N + nb] = make_float4(v0, v1, v2, v3);
            }
        }
    }
}

// ---------------- SPMM: out[d] = act(sum_e w[e]*sup[src[e]] + bias), F=256 ----------------

__global__ __launch_bounds__(256) void k_spmm(
    const unsigned short* __restrict__ sup, const int* __restrict__ es,
    const float* __restrict__ ew, const int* __restrict__ row_ptr,
    const void* __restrict__ bias, unsigned short* __restrict__ out,
    int Nn, int act, const int* __restrict__ dflag)
{
    const int wave = threadIdx.x >> 6;
    const int lane = threadIdx.x & 63;
    const int node = blockIdx.x * 4 + wave;
    if (node >= Nn) return;
    const bool bf = (*dflag != 0);

    const int half = lane >> 5;          // 0 or 1
    const int fl   = (lane & 31) * 8;    // feature base (8 f16 = 16 B)

    const int e0 = row_ptr[node], e1 = row_ptr[node + 1];
    float acc[8] = {};

    #pragma unroll 4
    for (int e = e0 + half; e < e1; e += 2) {
        int s = es[e];
        float w = ew[e];
        ushort8 u = *(const ushort8*)&sup[(long)s * 256 + fl];
        #pragma unroll
        for (int i = 0; i < 8; i++) acc[i] += w * h2f(u[i]);
    }

    #pragma unroll
    for (int i = 0; i < 8; i++) acc[i] += __shfl_xor(acc[i], 32, 64);

    if (half == 0) {
        float4 b0 = ld4(bias, fl, bf);
        float4 b1 = ld4(bias, fl + 4, bf);
        float bb[8] = {b0.x, b0.y, b0.z, b0.w, b1.x, b1.y, b1.z, b1.w};
        ushort8 o;
        #pragma unroll
        for (int i = 0; i < 8; i++) {
            float v = acc[i] + bb[i];
            if (act) v = fmaxf(v, 0.f);
            o[i] = f2h(v);
        }
        *(ushort8*)&out[(long)node * 256 + fl] = o;
    }
}

// ---------------- softmax over NC classes, one wave per row ----------------

__global__ __launch_bounds__(256) void k_softmax(
    const float* __restrict__ logits, void* __restrict__ out, int M, int NC,
    const int* __restrict__ dflag)
{
    const int wave = threadIdx.x >> 6;
    const int lane = threadIdx.x & 63;
    const int row = blockIdx.x * 4 + wave;
    if (row >= M) return;
    const bool bf = (*dflag != 0);

    float v = (lane < NC) ? logits[(long)row * NC + lane] : -INFINITY;
    float m = v;
    #pragma unroll
    for (int off = 32; off; off >>= 1) m = fmaxf(m, __shfl_xor(m, off, 64));
    float p = (lane < NC) ? expf(v - m) : 0.f;
    float s = p;
    #pragma unroll
    for (int off = 32; off; off >>= 1) s += __shfl_xor(s, off, 64);
    if (lane < NC) {
        float r = p / s;
        if (bf) ((unsigned short*)out)[(long)row * NC + lane] = f2bf(r);
        else    ((float*)out)[(long)row * NC + lane] = r;
    }
}

// ---------------- orchestration ----------------

extern "C" void kernel_launch(void* const* d_in, const int* in_sizes, int n_in,
                              void* d_out, int out_size, void* d_ws, size_t ws_size,
                              hipStream_t stream) {
    const void* x    = d_in[0];
    const int*  esrc = (const int*)d_in[1];
    const int*  edst = (const int*)d_in[2];
    const void* ewin = d_in[3];
    const void* w1 = d_in[4],  *b1 = d_in[5];
    const void* w2 = d_in[6],  *b2 = d_in[7];
    const void* wc1 = d_in[8], *bc1 = d_in[9];
    const void* wc2 = d_in[10], *bc2 = d_in[11];
    const void* wc3 = d_in[12], *bc3 = d_in[13];
    const void* wc4 = d_in[14], *bc4 = d_in[15];

    const int HID  = in_sizes[5];                 // 256
    const int IND  = in_sizes[4] / HID;           // 512
    const int HID2 = in_sizes[9];                 // 512
    const int NC   = in_sizes[15];                // 40
    const int M    = in_sizes[0] / IND;           // 100000
    const int E    = in_sizes[1];                 // 3200000

    char* ws = (char*)d_ws;
    int* dflag = (int*)ws;                                        // 256 B slot
    unsigned short* bufA = (unsigned short*)(ws + 256);           // sup (f16, 51.2 MB used)
    unsigned short* bufB = (unsigned short*)(ws + 256 + 102400000L);  // h1/h2 (f16)
    char*  wsC  = ws + 256 + 204800000L;                          // h3/h5 (f16) / CSR
    char*  wsD  = wsC + 204800000L;                               // h4 (f16) + WT tail
    unsigned short* bufC = (unsigned short*)wsC;
    unsigned short* bufD = (unsigned short*)wsD;

    // CSR arrays live inside bufC's region (dead before the MLP starts)
    int* counts  = (int*)wsC;
    int* row_ptr = counts + 100352;
    int* cursor  = row_ptr + 100352;
    int* bsums   = cursor + 100352;
    int* ex      = bsums + 1024;
    int* es      = ex + 100352;
    float* ewS   = (float*)(es + E);

    float* logits = (float*)bufA;   // reuse after support2 is dead (16 MB)

    // pre-transposed weight planes live in the tail of the h4 region
    _Float16* P = (_Float16*)(wsD + 103000000L);
    const long s_w1 = 256L * 512, s_w2 = 256L * 256, s_c1 = 512L * 256;
    const long s_c2 = 512L * 512, s_c3 = 512L * 512, s_c4 = 128L * 512;
    _Float16 *w1h = P,              *w1l = w1h + s_w1; unsigned short* w1b = (unsigned short*)(w1l + s_w1);
    _Float16 *w2h = (_Float16*)(w1b + s_w1), *w2l = w2h + s_w2; unsigned short* w2b = (unsigned short*)(w2l + s_w2);
    _Float16 *c1h = (_Float16*)(w2b + s_w2), *c1l = c1h + s_c1; unsigned short* c1b = (unsigned short*)(c1l + s_c1);
    _Float16 *c2h = (_Float16*)(c1b + s_c1), *c2l = c2h + s_c2; unsigned short* c2b = (unsigned short*)(c2l + s_c2);
    _Float16 *c3h = (_Float16*)(c2b + s_c2), *c3l = c3h + s_c3; unsigned short* c3b = (unsigned short*)(c3l + s_c3);
    _Float16 *c4h = (_Float16*)(c3b + s_c3), *c4l = c4h + s_c4; unsigned short* c4b = (unsigned short*)(c4l + s_c4);

    // 0. dtype sniff
    k_detect<<<1, 256, 0, stream>>>((const unsigned int*)x, dflag);

    // 0b. weight prep (transpose + f16 hi/lo + bf16), all tiny
    k_prep<<<dim3(IND / 256, HID),  256, 0, stream>>>(w1,  IND,  HID,  w1h, w1l, w1b, dflag);
    k_prep<<<dim3(HID / 256, HID),  256, 0, stream>>>(w2,  HID,  HID,  w2h, w2l, w2b, dflag);
    k_prep<<<dim3(HID / 256, HID2), 256, 0, stream>>>(wc1, HID,  HID2, c1h, c1l, c1b, dflag);
    k_prep<<<dim3(HID2 / 256, HID2),256, 0, stream>>>(wc2, HID2, HID2, c2h, c2l, c2b, dflag);
    k_prep<<<dim3(HID2 / 256, HID2),256, 0, stream>>>(wc3, HID2, HID2, c3h, c3l, c3b, dflag);
    k_prep<<<dim3(HID2 / 256, 128), 256, 0, stream>>>(wc4, HID2, NC,   c4h, c4l, c4b, dflag);

    // 1. CSR build
    hipMemsetAsync(counts, 0, 100352 * sizeof(int), stream);
    hipMemsetAsync(cursor, 0, 100352 * sizeof(int), stream);
    k_hist<<<(E + 255) / 256, 256, 0, stream>>>(edst, E, counts);
    int nb = (M + 1023) / 1024;                                   // 98
    k_scan_a<<<nb, 256, 0, stream>>>(counts, M, ex, bsums);
    k_scan_b<<<1, 256, 0, stream>>>(bsums, nb);
    k_scan_c<<<(M + 255) / 256, 256, 0, stream>>>(ex, bsums, M, E, row_ptr);
    k_scatter<<<(E + 255) / 256, 256, 0, stream>>>(esrc, edst, ewin, dflag, row_ptr, cursor, E, es, ewS);

    const int gm128 = (M + 127) / 128;   // 782
    dim3 blk(256);

    // 2. support1 = x @ w1                      [M,512]@[512,256] -> bufA (f16)
    k_gemm<0><<<dim3(HID / 128, gm128), blk, 0, stream>>>(x, w1h, w1l, w1b, nullptr, bufA, M, IND, HID, 2, 0, dflag);
    // 3. h1 = relu(spmm(support1) + b1)        -> bufB (f16)
    k_spmm<<<(M + 3) / 4, blk, 0, stream>>>(bufA, es, ewS, row_ptr, b1, bufB, M, 1, dflag);
    // 4. support2 = h1 @ w2                    -> bufA (f16)
    k_gemm<2><<<dim3(HID / 128, gm128), blk, 0, stream>>>(bufB, w2h, w2l, w2b, nullptr, bufA, M, HID, HID, 2, 0, dflag);
    // 5. h2 = spmm(support2) + b2              -> bufB (f16)
    k_spmm<<<(M + 3) / 4, blk, 0, stream>>>(bufA, es, ewS, row_ptr, b2, bufB, M, 0, dflag);
    // 6. h3 = relu(h2 @ wc1 + bc1)             [M,256]@[256,512] -> bufC (f16, CSR now dead)
    k_gemm<2><<<dim3(HID2 / 128, gm128), blk, 0, stream>>>(bufB, c1h, c1l, c1b, bc1, bufC, M, HID, HID2, 2, 1, dflag);
    // 7. h4 = relu(h3 @ wc2 + bc2)             -> bufD (f16)
    k_gemm<2><<<dim3(HID2 / 128, gm128), blk, 0, stream>>>(bufC, c2h, c2l, c2b, bc2, bufD, M, HID2, HID2, 2, 1, dflag);
    // 8. h5 = relu(h4 @ wc3 + bc3)             -> bufC (f16)
    k_gemm<2><<<dim3(HID2 / 128, gm128), blk, 0, stream>>>(bufD, c3h, c3l, c3b, bc3, bufC, M, HID2, HID2, 2, 1, dflag);
    // 9. logits = h5 @ wc4 + bc4               [M,512]@[512,40] -> bufA (fp32)
    k_gemm<2><<<dim3(1, gm128), blk, 0, stream>>>(bufC, c4h, c4l, c4b, bc4, logits, M, HID2, NC, 0, 0, dflag);
    // 10. softmax -> d_out
    k_softmax<<<(M + 3) / 4, blk, 0, stream>>>(logits, d_out, M, NC, dflag);
}